// Round 1
// baseline (880.346 us; speedup 1.0000x reference)
//
#include <hip/hip_runtime.h>

// Problem constants
#define BB 8
#define NN 128
#define CC 64
#define LL 3
#define HH 128
#define NEG 0.01f
#define NPOS (BB*NN*NN)   // 131072

// Workspace layout (in floats)
#define OFF_H    0L            // 8388608
#define OFF_RS   8388608L      // 65536  rowsum[n][i][c]
#define OFF_CS   8454144L      // 65536  colsum[n][j][c]
#define OFF_DG   8519680L      // 65536  diag[n][i][c]
#define OFF_TR   8585216L      // 512    trace[n][c]
#define OFF_TT   8585728L      // 512    total[n][c]
#define OFF_U    8586240L      // 65536
#define OFF_V    8651776L      // 65536
#define OFF_D    8717312L      // 65536
#define OFF_W1T  8782848L      // L*64*128
#define OFF_W2T  8807424L      // L*128*128
#define OFF_W3T  8856576L      // L*128*64
#define OFF_C9   8881152L      // L*64*64
#define OFF_C10  8893440L      // L*64*64
// total 8905728 floats = ~34 MB

__device__ __forceinline__ float leaky(float v) { return v >= 0.f ? v : NEG * v; }

// ---------------- prep: transpose weights to [k][out], extract c9/c10 ----------------
__global__ void prep_kernel(const float* __restrict__ w1, const float* __restrict__ w2,
                            const float* __restrict__ w3, const float* __restrict__ coefs,
                            float* __restrict__ ws) {
    long idx = (long)blockIdx.x * 256 + threadIdx.x;
    if (idx < 24576) {                       // w1T[l][k][h] = w1[l][h][k], w1:(L,H,C)
        int l = (int)(idx / 8192); int r = (int)(idx % 8192); int k = r >> 7, h = r & 127;
        ws[OFF_W1T + idx] = w1[((long)l*HH + h)*CC + k];
    } else if (idx < 73728) {                // w2T[l][k][h] = w2[l][h][k], w2:(L,H,H)
        long r2 = idx - 24576; int l = (int)(r2 / 16384); int r = (int)(r2 % 16384); int k = r >> 7, h = r & 127;
        ws[OFF_W2T + r2] = w2[((long)l*HH + h)*HH + k];
    } else if (idx < 98304) {                // w3T[l][k][c] = w3[l][c][k], w3:(L,C,H)
        long r3 = idx - 73728; int l = (int)(r3 / 8192); int r = (int)(r3 % 8192); int k = r >> 6, c = r & 63;
        ws[OFF_W3T + r3] = w3[((long)l*CC + c)*HH + k];
    } else if (idx < 110592) {               // c9[l][d][s]
        long r4 = idx - 98304; int l = (int)(r4 / 4096); int q = (int)(r4 % 4096); int d = q >> 6, s = q & 63;
        ws[OFF_C9 + r4] = coefs[(((long)l*CC + d)*CC + s)*15 + 9];
    } else if (idx < 122880) {               // c10[l][d][s]
        long r5 = idx - 110592; int l = (int)(r5 / 4096); int q = (int)(r5 % 4096); int d = q >> 6, s = q & 63;
        ws[OFF_C10 + r5] = coefs[(((long)l*CC + d)*CC + s)*15 + 10];
    }
}

// ---------------- fused 3-stage MLP: h = leaky(leaky(leaky(x W1^T+b1) W2^T+b2) W3^T+b3) * mask ---
// 64 positions per block; lane owns a position; wave owns an output chunk.
// Weights read via wave-uniform indices -> scalar loads. x/h1/h2 in XOR-swizzled LDS rows.
__global__ __launch_bounds__(256, 2) void mlp_kernel(
    const float* __restrict__ xin, const float* __restrict__ mask,
    const float* __restrict__ b1, const float* __restrict__ b2, const float* __restrict__ b3,
    const float* __restrict__ wt1, const float* __restrict__ wt2, const float* __restrict__ wt3,
    float* __restrict__ hout)
{
    __shared__ float xt[64*64];
    __shared__ float h1t[64*128];
    __shared__ float h2t[64*128];
    const int t = threadIdx.x;
    const int lane = t & 63;
    const int w = __builtin_amdgcn_readfirstlane(t >> 6);
    const long pos0 = (long)blockIdx.x * 64;

    const float* xsrc = xin + pos0 * CC;
    #pragma unroll
    for (int rep = 0; rep < 16; ++rep) {
        int idx = rep * 256 + t;
        int p = idx >> 6, k = idx & 63;
        xt[p*64 + (k ^ (p & 31))] = xsrc[idx];
    }
    __syncthreads();

    // stage 1: 128 outputs; wave w -> [w*32, w*32+32)
    #pragma unroll
    for (int chunk = 0; chunk < 2; ++chunk) {
        const int h0 = w*32 + chunk*16;
        float acc[16];
        #pragma unroll
        for (int c = 0; c < 16; ++c) acc[c] = b1[h0 + c];
        for (int k = 0; k < 64; ++k) {
            const float xv = xt[lane*64 + (k ^ (lane & 31))];
            const float* wr = wt1 + k*HH + h0;
            #pragma unroll
            for (int c = 0; c < 16; ++c) acc[c] = fmaf(xv, wr[c], acc[c]);
        }
        #pragma unroll
        for (int c = 0; c < 16; ++c)
            h1t[lane*128 + ((h0 + c) ^ (lane & 31))] = leaky(acc[c]);
    }
    __syncthreads();

    // stage 2: 128 outputs; wave w -> [w*32, w*32+32)
    #pragma unroll
    for (int chunk = 0; chunk < 2; ++chunk) {
        const int h0 = w*32 + chunk*16;
        float acc[16];
        #pragma unroll
        for (int c = 0; c < 16; ++c) acc[c] = b2[h0 + c];
        for (int k = 0; k < 128; ++k) {
            const float xv = h1t[lane*128 + (k ^ (lane & 31))];
            const float* wr = wt2 + k*HH + h0;
            #pragma unroll
            for (int c = 0; c < 16; ++c) acc[c] = fmaf(xv, wr[c], acc[c]);
        }
        #pragma unroll
        for (int c = 0; c < 16; ++c)
            h2t[lane*128 + ((h0 + c) ^ (lane & 31))] = leaky(acc[c]);
    }
    __syncthreads();

    // stage 3: 64 outputs; wave w -> [w*16, w*16+16)
    {
        const int h0 = w*16;
        float acc[16];
        #pragma unroll
        for (int c = 0; c < 16; ++c) acc[c] = b3[h0 + c];
        for (int k = 0; k < 128; ++k) {
            const float xv = h2t[lane*128 + (k ^ (lane & 31))];
            const float* wr = wt3 + k*CC + h0;
            #pragma unroll
            for (int c = 0; c < 16; ++c) acc[c] = fmaf(xv, wr[c], acc[c]);
        }
        const float mv = mask[pos0 + lane];
        float4 r[4];
        #pragma unroll
        for (int c = 0; c < 16; ++c) ((float*)r)[c] = leaky(acc[c]) * mv;
        float4* dst = (float4*)(hout + (pos0 + lane)*CC + h0);
        #pragma unroll
        for (int q = 0; q < 4; ++q) dst[q] = r[q];
    }
}

// ---------------- reductions: rowsum, colsum, diag ----------------
__global__ __launch_bounds__(256) void reduce_kernel(const float* __restrict__ h,
                                                     float* __restrict__ rowsum,
                                                     float* __restrict__ colsum,
                                                     float* __restrict__ diag) {
    const int br = blockIdx.x;            // n*128 + r
    const int n = br >> 7, r = br & 127;
    const int t = threadIdx.x, c = t & 63, g = t >> 6;
    __shared__ float red[4][64];
    const float* base_row = h + ((long)(n*NN + r) * NN) * CC;
    float acc = 0.f;
    for (int j = g; j < NN; j += 4) acc += base_row[j*CC + c];
    red[g][c] = acc;
    __syncthreads();
    if (t < 64) rowsum[(long)br*CC + c] = red[0][c] + red[1][c] + red[2][c] + red[3][c];
    __syncthreads();
    const float* base_col = h + ((long)n*NN*NN + r) * CC;
    float acc2 = 0.f;
    for (int i = g; i < NN; i += 4) acc2 += base_col[(long)i*NN*CC + c];
    red[g][c] = acc2;
    __syncthreads();
    if (t < 64) {
        colsum[(long)br*CC + c] = red[0][c] + red[1][c] + red[2][c] + red[3][c];
        diag[(long)br*CC + c] = base_row[r*CC + c];
    }
}

// ---------------- trace/total ----------------
__global__ __launch_bounds__(256) void trace_total_kernel(const float* __restrict__ rowsum,
                                                          const float* __restrict__ diag,
                                                          float* __restrict__ trace,
                                                          float* __restrict__ total) {
    const int n = blockIdx.x;
    const int t = threadIdx.x, c = t & 63, g = t >> 6;
    __shared__ float ra[4][64], rb[4][64];
    float a = 0.f, b = 0.f;
    for (int i = g; i < NN; i += 4) {
        a += rowsum[((long)n*NN + i)*CC + c];
        b += diag[((long)n*NN + i)*CC + c];
    }
    ra[g][c] = a; rb[g][c] = b;
    __syncthreads();
    if (t < 64) {
        total[(long)n*CC + c] = ra[0][c] + ra[1][c] + ra[2][c] + ra[3][c];
        trace[(long)n*CC + c] = rb[0][c] + rb[1][c] + rb[2][c] + rb[3][c];
    }
}

// ---------------- U/V/D precompute (W and diag-consts folded in) ----------------
__global__ __launch_bounds__(256) void uvd_kernel(const float* __restrict__ rowsum,
                                                  const float* __restrict__ colsum,
                                                  const float* __restrict__ diag,
                                                  const float* __restrict__ trace,
                                                  const float* __restrict__ total,
                                                  const float* __restrict__ coefs, int layer,
                                                  float* __restrict__ U, float* __restrict__ V,
                                                  float* __restrict__ D) {
    const int bi = blockIdx.x;            // n*128 + i
    const int n = bi >> 7, i = bi & 127;
    const int t = threadIdx.x;
    if (t >= 192) return;
    const int which = t >> 6, s = t & 63;
    const float* cf = coefs + (long)layer*CC*CC*15;
    const long rbase = ((long)n*NN + i)*CC;
    float acc = 0.f;
    for (int d = 0; d < CC; ++d) {
        const float rs = rowsum[rbase + d];
        const float cs = colsum[rbase + d];
        const float dg = diag[rbase + d];
        const float tr = trace[(long)n*CC + d];
        const float tt = total[(long)n*CC + d];
        const float* cds = cf + ((long)d*CC + s)*15;
        if (which == 0)       acc += cds[5]*cs + cds[6]*rs + cds[11]*dg + cds[13]*tr + cds[14]*tt;
        else if (which == 1)  acc += cds[7]*cs + cds[8]*rs + cds[12]*dg;
        else                  acc += cds[0]*dg + cds[1]*tr + cds[2]*rs + cds[3]*cs + cds[4]*tt;
    }
    float* dst = (which == 0) ? U : (which == 1) ? V : D;
    dst[rbase + s] = acc;
}

// ---------------- Eq2to2 finalize: per-element A + At + broadcast terms, leaky, mask ------------
__global__ __launch_bounds__(256, 2) void eq_kernel(
    const float* __restrict__ h, const float* __restrict__ mask,
    const float* __restrict__ c9, const float* __restrict__ c10,
    const float* __restrict__ U, const float* __restrict__ V, const float* __restrict__ D,
    const float* __restrict__ bias, const float* __restrict__ dbias,
    float* __restrict__ out)
{
    __shared__ float hA[64*65];
    __shared__ float hT[64*65];
    const int t = threadIdx.x;
    const int sgw = __builtin_amdgcn_readfirstlane(t >> 6);
    const int p = t & 63, pi = p >> 3, pj = p & 7;
    const int jt = blockIdx.x, it = blockIdx.y, n = blockIdx.z;
    const int i0 = it*8, j0 = jt*8;

    #pragma unroll
    for (int rep = 0; rep < 16; ++rep) {
        int idx = rep*256 + t;
        int a = idx >> 9, b = (idx >> 6) & 7, d = idx & 63;
        hA[(a*8+b)*65 + d] = h[(((long)n*NN + i0+a)*NN + j0+b)*CC + d];
        hT[(b*8+a)*65 + d] = h[(((long)n*NN + j0+a)*NN + i0+b)*CC + d];
    }
    __syncthreads();

    const int s0 = sgw * 16;
    float acc[16];
    #pragma unroll
    for (int c = 0; c < 16; ++c) acc[c] = 0.f;
    for (int d = 0; d < CC; ++d) {
        const float va = hA[p*65 + d];
        const float vt = hT[p*65 + d];
        const float* w9  = c9  + d*CC + s0;
        const float* w10 = c10 + d*CC + s0;
        #pragma unroll
        for (int c = 0; c < 16; ++c) acc[c] = fmaf(va, w9[c], fmaf(vt, w10[c], acc[c]));
    }
    const int i = i0 + pi, j = j0 + pj;
    const long pix = ((long)n*NN + i)*NN + j;
    const float mv = mask[pix];
    const float* Urow = U + ((long)n*NN + i)*CC + s0;
    const float* Vrow = V + ((long)n*NN + j)*CC + s0;
    const float* Drow = D + ((long)n*NN + i)*CC + s0;
    const bool isdiag = (i == j);
    float4 r[4];
    #pragma unroll
    for (int c = 0; c < 16; ++c) {
        float v = acc[c] + Urow[c] + Vrow[c] + bias[s0 + c];
        if (isdiag) v += Drow[c] + dbias[s0 + c];
        ((float*)r)[c] = leaky(v) * mv;
    }
    float4* dst = (float4*)(out + pix*CC + s0);
    #pragma unroll
    for (int q = 0; q < 4; ++q) dst[q] = r[q];
}

extern "C" void kernel_launch(void* const* d_in, const int* in_sizes, int n_in,
                              void* d_out, int out_size, void* d_ws, size_t ws_size,
                              hipStream_t stream) {
    const float* x     = (const float*)d_in[0];
    const float* mask  = (const float*)d_in[1];
    const float* w1    = (const float*)d_in[2];
    const float* b1    = (const float*)d_in[3];
    const float* w2    = (const float*)d_in[4];
    const float* b2    = (const float*)d_in[5];
    const float* w3    = (const float*)d_in[6];
    const float* b3    = (const float*)d_in[7];
    const float* coefs = (const float*)d_in[8];
    const float* bias  = (const float*)d_in[9];
    const float* dbias = (const float*)d_in[10];
    float* out = (float*)d_out;
    float* ws  = (float*)d_ws;

    float* h      = ws + OFF_H;
    float* rowsum = ws + OFF_RS;
    float* colsum = ws + OFF_CS;
    float* diag   = ws + OFF_DG;
    float* trace  = ws + OFF_TR;
    float* total  = ws + OFF_TT;
    float* U      = ws + OFF_U;
    float* V      = ws + OFF_V;
    float* D      = ws + OFF_D;

    prep_kernel<<<480, 256, 0, stream>>>(w1, w2, w3, coefs, ws);

    const float* cur = x;
    for (int l = 0; l < LL; ++l) {
        mlp_kernel<<<NPOS/64, 256, 0, stream>>>(
            cur, mask, b1 + l*HH, b2 + l*HH, b3 + l*CC,
            ws + OFF_W1T + (long)l*CC*HH, ws + OFF_W2T + (long)l*HH*HH,
            ws + OFF_W3T + (long)l*HH*CC, h);
        reduce_kernel<<<BB*NN, 256, 0, stream>>>(h, rowsum, colsum, diag);
        trace_total_kernel<<<BB, 256, 0, stream>>>(rowsum, diag, trace, total);
        uvd_kernel<<<BB*NN, 256, 0, stream>>>(rowsum, colsum, diag, trace, total,
                                              coefs, l, U, V, D);
        eq_kernel<<<dim3(NN/8, NN/8, BB), 256, 0, stream>>>(
            h, mask, ws + OFF_C9 + (long)l*CC*CC, ws + OFF_C10 + (long)l*CC*CC,
            U, V, D, bias + l*CC, dbias + l*CC, out);
        cur = out;
    }
}

// Round 2
// 449.880 us; speedup vs baseline: 1.9568x; 1.9568x over previous
//
#include <hip/hip_runtime.h>

// Problem constants
#define BB 8
#define NN 128
#define CC 64
#define LL 3
#define HH 128
#define NEG 0.01f
#define NPOS (BB*NN*NN)   // 131072

typedef __attribute__((ext_vector_type(8))) short shortx8;   // 8 bf16 = 4 VGPRs
typedef __attribute__((ext_vector_type(4))) float f32x4;

// Workspace layout (in floats)
#define OFF_H    0L            // 8388608
#define OFF_RS   8388608L      // 65536  rowsum[n][i][c]
#define OFF_CS   8454144L      // 65536  colsum[n][j][c]
#define OFF_DG   8519680L      // 65536  diag[n][i][c]
#define OFF_TR   8585216L      // 512    trace[n][c]
#define OFF_TT   8585728L      // 512    total[n][c]
#define OFF_U    8586240L      // 65536
#define OFF_V    8651776L      // 65536
#define OFF_D    8717312L      // 65536
#define OFF_C9   8782848L      // L*64*64 = 12288
#define OFF_C10  8795136L      // 12288
#define OFF_WB   8807424L      // bf16 weights: 98304 shorts = 49152 floats
// total 8856576 floats ~= 33.8 MB

__device__ __forceinline__ float leaky(float v) { return v >= 0.f ? v : NEG * v; }

__device__ __forceinline__ short f2bf(float f) {   // RNE float -> bf16
    unsigned u = __builtin_bit_cast(unsigned, f);
    u += 0x7fff + ((u >> 16) & 1);
    return (short)(u >> 16);
}

// ---------------- prep: bf16 weights (natural [out][in] layout), extract c9/c10 ----------------
__global__ void prep_kernel(const float* __restrict__ w1, const float* __restrict__ w2,
                            const float* __restrict__ w3, const float* __restrict__ coefs,
                            float* __restrict__ ws) {
    long idx = (long)blockIdx.x * 256 + threadIdx.x;
    short* wb = (short*)(ws + OFF_WB);
    if (idx < 24576) {                       // wb1[l][h][c]
        wb[idx] = f2bf(w1[idx]);
    } else if (idx < 73728) {                // wb2[l][h][k]
        wb[idx] = f2bf(w2[idx - 24576]);
    } else if (idx < 98304) {                // wb3[l][c][k]
        wb[idx] = f2bf(w3[idx - 73728]);
    } else if (idx < 110592) {               // c9[l][d][s]
        long r4 = idx - 98304; int l = (int)(r4 / 4096); int q = (int)(r4 % 4096); int d = q >> 6, s = q & 63;
        ws[OFF_C9 + r4] = coefs[(((long)l*CC + d)*CC + s)*15 + 9];
    } else if (idx < 122880) {               // c10[l][d][s]
        long r5 = idx - 110592; int l = (int)(r5 / 4096); int q = (int)(r5 % 4096); int d = q >> 6, s = q & 63;
        ws[OFF_C10 + r5] = coefs[(((long)l*CC + d)*CC + s)*15 + 10];
    }
}

// ---------------- MFMA fused 3-stage MLP ----------------
// 64 positions/block, 4 waves. bf16 operands, fp32 accumulate.
// LDS: [0,8192)=x tile (64x64 bf16, stride 128B, XOR-swizzled)
//      [8192,24576)=h1 (64x128 bf16, stride 256B), [24576,40960)=h2.
// Stage-3 fp32 result staged at base 0 (aliases dead x/h1) for coalesced store.
__global__ __launch_bounds__(256, 4) void mlp_kernel(
    const float* __restrict__ xin, const float* __restrict__ mask,
    const float* __restrict__ b1, const float* __restrict__ b2, const float* __restrict__ b3,
    const short* __restrict__ wb1, const short* __restrict__ wb2, const short* __restrict__ wb3,
    float* __restrict__ hout)
{
    __shared__ __align__(16) char lds[40960];
    const int t = threadIdx.x;
    const int lane = t & 63;
    const int w = t >> 6;
    const long pos0 = (long)blockIdx.x * 64;

    const int arow = lane & 15;        // fragment row/col within 16
    const int kgrp = lane >> 4;        // k-group 0..3 (8 bf16 each)
    const int kb = kgrp * 16;          // byte offset of k-group

    // ---- load x tile: 64 rows x 64 f32 -> bf16 swizzled ----
    {
        const int row = t >> 2, q = t & 3;
        const float4* src = (const float4*)(xin + (pos0 + row)*CC + q*16);
        short sv[16];
        #pragma unroll
        for (int i = 0; i < 4; ++i) {
            float4 v = src[i];
            sv[i*4+0] = f2bf(v.x); sv[i*4+1] = f2bf(v.y);
            sv[i*4+2] = f2bf(v.z); sv[i*4+3] = f2bf(v.w);
        }
        const int swz = (row & 7) << 4;
        *(shortx8*)(&lds[row*128 + ((q*32 +  0) ^ swz)]) = *(shortx8*)(&sv[0]);
        *(shortx8*)(&lds[row*128 + ((q*32 + 16) ^ swz)]) = *(shortx8*)(&sv[8]);
    }
    __syncthreads();

    // ---- stage 1: (64x64)x(64x128) -> h1 ----
    {
        const int n0 = w * 32;
        f32x4 acc[4][2];
        #pragma unroll
        for (int m = 0; m < 4; ++m)
            #pragma unroll
            for (int n = 0; n < 2; ++n) acc[m][n] = (f32x4){0.f,0.f,0.f,0.f};
        #pragma unroll
        for (int kk = 0; kk < 2; ++kk) {
            shortx8 a[4];
            #pragma unroll
            for (int m = 0; m < 4; ++m) {
                const int row = m*16 + arow;
                a[m] = *(const shortx8*)(&lds[row*128 + ((kk*64 + kb) ^ ((row & 7) << 4))]);
            }
            #pragma unroll
            for (int n = 0; n < 2; ++n) {
                const shortx8 b = *(const shortx8*)(wb1 + (n0 + n*16 + arow)*64 + kk*32 + kgrp*8);
                #pragma unroll
                for (int m = 0; m < 4; ++m)
                    acc[m][n] = __builtin_amdgcn_mfma_f32_16x16x32_bf16(a[m], b, acc[m][n], 0, 0, 0);
            }
        }
        #pragma unroll
        for (int n = 0; n < 2; ++n) {
            const int col = n0 + n*16 + arow;
            const float bv = b1[col];
            #pragma unroll
            for (int m = 0; m < 4; ++m)
                #pragma unroll
                for (int r = 0; r < 4; ++r) {
                    const int row = m*16 + kgrp*4 + r;
                    *(short*)(&lds[8192 + row*256 + ((col*2) ^ ((row & 7) << 4))]) =
                        f2bf(leaky(acc[m][n][r] + bv));
                }
        }
    }
    __syncthreads();

    // ---- stage 2: (64x128)x(128x128) -> h2 ----
    {
        const int n0 = w * 32;
        f32x4 acc[4][2];
        #pragma unroll
        for (int m = 0; m < 4; ++m)
            #pragma unroll
            for (int n = 0; n < 2; ++n) acc[m][n] = (f32x4){0.f,0.f,0.f,0.f};
        #pragma unroll
        for (int kk = 0; kk < 4; ++kk) {
            shortx8 a[4];
            #pragma unroll
            for (int m = 0; m < 4; ++m) {
                const int row = m*16 + arow;
                a[m] = *(const shortx8*)(&lds[8192 + row*256 + ((kk*64 + kb) ^ ((row & 7) << 4))]);
            }
            #pragma unroll
            for (int n = 0; n < 2; ++n) {
                const shortx8 b = *(const shortx8*)(wb2 + (n0 + n*16 + arow)*128 + kk*32 + kgrp*8);
                #pragma unroll
                for (int m = 0; m < 4; ++m)
                    acc[m][n] = __builtin_amdgcn_mfma_f32_16x16x32_bf16(a[m], b, acc[m][n], 0, 0, 0);
            }
        }
        #pragma unroll
        for (int n = 0; n < 2; ++n) {
            const int col = n0 + n*16 + arow;
            const float bv = b2[col];
            #pragma unroll
            for (int m = 0; m < 4; ++m)
                #pragma unroll
                for (int r = 0; r < 4; ++r) {
                    const int row = m*16 + kgrp*4 + r;
                    *(short*)(&lds[24576 + row*256 + ((col*2) ^ ((row & 7) << 4))]) =
                        f2bf(leaky(acc[m][n][r] + bv));
                }
        }
    }
    __syncthreads();

    // ---- stage 3: (64x128)x(128x64) -> fp32 out tile at LDS base 0 ----
    {
        const int n0 = w * 16;
        f32x4 acc[4];
        #pragma unroll
        for (int m = 0; m < 4; ++m) acc[m] = (f32x4){0.f,0.f,0.f,0.f};
        #pragma unroll
        for (int kk = 0; kk < 4; ++kk) {
            shortx8 a[4];
            #pragma unroll
            for (int m = 0; m < 4; ++m) {
                const int row = m*16 + arow;
                a[m] = *(const shortx8*)(&lds[24576 + row*256 + ((kk*64 + kb) ^ ((row & 7) << 4))]);
            }
            const shortx8 b = *(const shortx8*)(wb3 + (n0 + arow)*128 + kk*32 + kgrp*8);
            #pragma unroll
            for (int m = 0; m < 4; ++m)
                acc[m] = __builtin_amdgcn_mfma_f32_16x16x32_bf16(a[m], b, acc[m], 0, 0, 0);
        }
        const int col = n0 + arow;
        const float bv = b3[col];
        #pragma unroll
        for (int m = 0; m < 4; ++m)
            #pragma unroll
            for (int r = 0; r < 4; ++r) {
                const int row = m*16 + kgrp*4 + r;
                *(float*)(&lds[row*256 + ((col*4) ^ ((row & 7) << 4))]) =
                    leaky(acc[m][r] + bv);
            }
    }
    __syncthreads();

    // ---- coalesced masked store: 64 rows x 64 f32 ----
    {
        const int row = t >> 2, q = t & 3;
        const float mv = mask[pos0 + row];
        const int swz = (row & 7) << 4;
        float4* dst = (float4*)(hout + (pos0 + row)*CC + q*16);
        #pragma unroll
        for (int i = 0; i < 4; ++i) {
            float4 v = *(float4*)(&lds[row*256 + ((q*64 + i*16) ^ swz)]);
            v.x *= mv; v.y *= mv; v.z *= mv; v.w *= mv;
            dst[i] = v;
        }
    }
}

// ---------------- reductions: rowsum, colsum, diag ----------------
__global__ __launch_bounds__(256) void reduce_kernel(const float* __restrict__ h,
                                                     float* __restrict__ rowsum,
                                                     float* __restrict__ colsum,
                                                     float* __restrict__ diag) {
    const int br = blockIdx.x;            // n*128 + r
    const int n = br >> 7, r = br & 127;
    const int t = threadIdx.x, c = t & 63, g = t >> 6;
    __shared__ float red[4][64];
    const float* base_row = h + ((long)(n*NN + r) * NN) * CC;
    float acc = 0.f;
    for (int j = g; j < NN; j += 4) acc += base_row[j*CC + c];
    red[g][c] = acc;
    __syncthreads();
    if (t < 64) rowsum[(long)br*CC + c] = red[0][c] + red[1][c] + red[2][c] + red[3][c];
    __syncthreads();
    const float* base_col = h + ((long)n*NN*NN + r) * CC;
    float acc2 = 0.f;
    for (int i = g; i < NN; i += 4) acc2 += base_col[(long)i*NN*CC + c];
    red[g][c] = acc2;
    __syncthreads();
    if (t < 64) {
        colsum[(long)br*CC + c] = red[0][c] + red[1][c] + red[2][c] + red[3][c];
        diag[(long)br*CC + c] = base_row[r*CC + c];
    }
}

// ---------------- trace/total ----------------
__global__ __launch_bounds__(256) void trace_total_kernel(const float* __restrict__ rowsum,
                                                          const float* __restrict__ diag,
                                                          float* __restrict__ trace,
                                                          float* __restrict__ total) {
    const int n = blockIdx.x;
    const int t = threadIdx.x, c = t & 63, g = t >> 6;
    __shared__ float ra[4][64], rb[4][64];
    float a = 0.f, b = 0.f;
    for (int i = g; i < NN; i += 4) {
        a += rowsum[((long)n*NN + i)*CC + c];
        b += diag[((long)n*NN + i)*CC + c];
    }
    ra[g][c] = a; rb[g][c] = b;
    __syncthreads();
    if (t < 64) {
        total[(long)n*CC + c] = ra[0][c] + ra[1][c] + ra[2][c] + ra[3][c];
        trace[(long)n*CC + c] = rb[0][c] + rb[1][c] + rb[2][c] + rb[3][c];
    }
}

// ---------------- U/V/D precompute ----------------
__global__ __launch_bounds__(256) void uvd_kernel(const float* __restrict__ rowsum,
                                                  const float* __restrict__ colsum,
                                                  const float* __restrict__ diag,
                                                  const float* __restrict__ trace,
                                                  const float* __restrict__ total,
                                                  const float* __restrict__ coefs, int layer,
                                                  float* __restrict__ U, float* __restrict__ V,
                                                  float* __restrict__ D) {
    const int bi = blockIdx.x;            // n*128 + i
    const int n = bi >> 7, i = bi & 127;
    const int t = threadIdx.x;
    if (t >= 192) return;
    const int which = t >> 6, s = t & 63;
    const float* cf = coefs + (long)layer*CC*CC*15;
    const long rbase = ((long)n*NN + i)*CC;
    float acc = 0.f;
    for (int d = 0; d < CC; ++d) {
        const float rs = rowsum[rbase + d];
        const float cs = colsum[rbase + d];
        const float dg = diag[rbase + d];
        const float tr = trace[(long)n*CC + d];
        const float tt = total[(long)n*CC + d];
        const float* cds = cf + ((long)d*CC + s)*15;
        if (which == 0)       acc += cds[5]*cs + cds[6]*rs + cds[11]*dg + cds[13]*tr + cds[14]*tt;
        else if (which == 1)  acc += cds[7]*cs + cds[8]*rs + cds[12]*dg;
        else                  acc += cds[0]*dg + cds[1]*tr + cds[2]*rs + cds[3]*cs + cds[4]*tt;
    }
    float* dst = (which == 0) ? U : (which == 1) ? V : D;
    dst[rbase + s] = acc;
}

// ---------------- Eq2to2 finalize ----------------
__global__ __launch_bounds__(256, 2) void eq_kernel(
    const float* __restrict__ h, const float* __restrict__ mask,
    const float* __restrict__ c9, const float* __restrict__ c10,
    const float* __restrict__ U, const float* __restrict__ V, const float* __restrict__ D,
    const float* __restrict__ bias, const float* __restrict__ dbias,
    float* __restrict__ out)
{
    __shared__ float hA[64*65];
    __shared__ float hT[64*65];
    const int t = threadIdx.x;
    const int sgw = __builtin_amdgcn_readfirstlane(t >> 6);
    const int p = t & 63, pi = p >> 3, pj = p & 7;
    const int jt = blockIdx.x, it = blockIdx.y, n = blockIdx.z;
    const int i0 = it*8, j0 = jt*8;

    #pragma unroll
    for (int rep = 0; rep < 16; ++rep) {
        int idx = rep*256 + t;
        int a = idx >> 9, b = (idx >> 6) & 7, d = idx & 63;
        hA[(a*8+b)*65 + d] = h[(((long)n*NN + i0+a)*NN + j0+b)*CC + d];
        hT[(b*8+a)*65 + d] = h[(((long)n*NN + j0+a)*NN + i0+b)*CC + d];
    }
    __syncthreads();

    const int s0 = sgw * 16;
    float acc[16];
    #pragma unroll
    for (int c = 0; c < 16; ++c) acc[c] = 0.f;
    for (int d = 0; d < CC; ++d) {
        const float va = hA[p*65 + d];
        const float vt = hT[p*65 + d];
        const float* w9  = c9  + d*CC + s0;
        const float* w10 = c10 + d*CC + s0;
        #pragma unroll
        for (int c = 0; c < 16; ++c) acc[c] = fmaf(va, w9[c], fmaf(vt, w10[c], acc[c]));
    }
    const int i = i0 + pi, j = j0 + pj;
    const long pix = ((long)n*NN + i)*NN + j;
    const float mv = mask[pix];
    const float* Urow = U + ((long)n*NN + i)*CC + s0;
    const float* Vrow = V + ((long)n*NN + j)*CC + s0;
    const float* Drow = D + ((long)n*NN + i)*CC + s0;
    const bool isdiag = (i == j);
    float4 r[4];
    #pragma unroll
    for (int c = 0; c < 16; ++c) {
        float v = acc[c] + Urow[c] + Vrow[c] + bias[s0 + c];
        if (isdiag) v += Drow[c] + dbias[s0 + c];
        ((float*)r)[c] = leaky(v) * mv;
    }
    float4* dst = (float4*)(out + pix*CC + s0);
    #pragma unroll
    for (int q = 0; q < 4; ++q) dst[q] = r[q];
}

extern "C" void kernel_launch(void* const* d_in, const int* in_sizes, int n_in,
                              void* d_out, int out_size, void* d_ws, size_t ws_size,
                              hipStream_t stream) {
    const float* x     = (const float*)d_in[0];
    const float* mask  = (const float*)d_in[1];
    const float* w1    = (const float*)d_in[2];
    const float* b1    = (const float*)d_in[3];
    const float* w2    = (const float*)d_in[4];
    const float* b2    = (const float*)d_in[5];
    const float* w3    = (const float*)d_in[6];
    const float* b3    = (const float*)d_in[7];
    const float* coefs = (const float*)d_in[8];
    const float* bias  = (const float*)d_in[9];
    const float* dbias = (const float*)d_in[10];
    float* out = (float*)d_out;
    float* ws  = (float*)d_ws;

    float* h      = ws + OFF_H;
    float* rowsum = ws + OFF_RS;
    float* colsum = ws + OFF_CS;
    float* diag   = ws + OFF_DG;
    float* trace  = ws + OFF_TR;
    float* total  = ws + OFF_TT;
    float* U      = ws + OFF_U;
    float* V      = ws + OFF_V;
    float* D      = ws + OFF_D;
    short* wb     = (short*)(ws + OFF_WB);

    prep_kernel<<<480, 256, 0, stream>>>(w1, w2, w3, coefs, ws);

    const float* cur = x;
    for (int l = 0; l < LL; ++l) {
        mlp_kernel<<<NPOS/64, 256, 0, stream>>>(
            cur, mask, b1 + l*HH, b2 + l*HH, b3 + l*CC,
            wb + (long)l*HH*CC, wb + 24576 + (long)l*HH*HH, wb + 73728 + (long)l*CC*HH,
            h);
        reduce_kernel<<<BB*NN, 256, 0, stream>>>(h, rowsum, colsum, diag);
        trace_total_kernel<<<BB, 256, 0, stream>>>(rowsum, diag, trace, total);
        uvd_kernel<<<BB*NN, 256, 0, stream>>>(rowsum, colsum, diag, trace, total,
                                              coefs, l, U, V, D);
        eq_kernel<<<dim3(NN/8, NN/8, BB), 256, 0, stream>>>(
            h, mask, ws + OFF_C9 + (long)l*CC*CC, ws + OFF_C10 + (long)l*CC*CC,
            U, V, D, bias + l*CC, dbias + l*CC, out);
        cur = out;
    }
}

// Round 3
// 390.038 us; speedup vs baseline: 2.2571x; 1.1534x over previous
//
#include <hip/hip_runtime.h>

// Problem constants
#define BB 8
#define NN 128
#define CC 64
#define LL 3
#define HH 128
#define NEG 0.01f
#define NPOS (BB*NN*NN)   // 131072

typedef __attribute__((ext_vector_type(8))) short shortx8;   // 8 bf16 = 4 VGPRs
typedef __attribute__((ext_vector_type(4))) float f32x4;

// Workspace layout (in floats)
#define OFF_H    0L            // 8388608
#define OFF_RS   8388608L      // 65536  rowsum[n][i][c]
#define OFF_CS   8454144L      // 65536  colsum[n][j][c]
#define OFF_DG   8519680L      // 65536  diag[n][i][c]
#define OFF_TR   8585216L      // 512    trace[n][c]
#define OFF_TT   8585728L      // 512    total[n][c]
#define OFF_U    8586240L      // 65536
#define OFF_V    8651776L      // 65536
#define OFF_D    8717312L      // 65536
#define OFF_WB   8782848L      // bf16 region: 147456 shorts = 73728 floats
// bf16 region layout (short offsets from OFF_WB base):
//   wb1 @0 (L*128*64=24576), wb2 @24576 (L*128*128=49152), wb3 @73728 (L*64*128=24576)
//   c9hi @98304, c9lo @110592, c10hi @122880, c10lo @135168 (each L*64*64=12288, [l][s][d])
// total 8856576 floats ~= 35.4 MB

__device__ __forceinline__ float leaky(float v) { return v >= 0.f ? v : NEG * v; }

__device__ __forceinline__ short f2bf(float f) {   // RNE float -> bf16
    unsigned u = __builtin_bit_cast(unsigned, f);
    u += 0x7fff + ((u >> 16) & 1);
    return (short)(u >> 16);
}
__device__ __forceinline__ float bf2f(short s) {
    unsigned u = ((unsigned)(unsigned short)s) << 16;
    return __builtin_bit_cast(float, u);
}

// ---------------- prep: bf16 weights + split-bf16 c9/c10 ([s][d] layout) ----------------
__global__ void prep_kernel(const float* __restrict__ w1, const float* __restrict__ w2,
                            const float* __restrict__ w3, const float* __restrict__ coefs,
                            float* __restrict__ ws) {
    long idx = (long)blockIdx.x * 256 + threadIdx.x;
    short* sb = (short*)(ws + OFF_WB);
    if (idx < 24576) {                       // wb1[l][h][c]
        sb[idx] = f2bf(w1[idx]);
    } else if (idx < 73728) {                // wb2[l][h][k]
        sb[idx] = f2bf(w2[idx - 24576]);
    } else if (idx < 98304) {                // wb3[l][c][k]
        sb[idx] = f2bf(w3[idx - 73728]);
    } else if (idx < 110592) {               // c9hi/lo[l][s][d]
        long r = idx - 98304; int l = (int)(r / 4096); int q = (int)(r % 4096);
        int s = q >> 6, d = q & 63;
        float v = coefs[(((long)l*CC + d)*CC + s)*15 + 9];
        short hi = f2bf(v);
        sb[98304 + r]  = hi;
        sb[110592 + r] = f2bf(v - bf2f(hi));
    } else if (idx < 122880) {               // c10hi/lo[l][s][d]
        long r = idx - 110592; int l = (int)(r / 4096); int q = (int)(r % 4096);
        int s = q >> 6, d = q & 63;
        float v = coefs[(((long)l*CC + d)*CC + s)*15 + 10];
        short hi = f2bf(v);
        sb[122880 + r] = hi;
        sb[135168 + r] = f2bf(v - bf2f(hi));
    }
}

// ---------------- MFMA fused 3-stage MLP ----------------
__global__ __launch_bounds__(256, 4) void mlp_kernel(
    const float* __restrict__ xin, const float* __restrict__ mask,
    const float* __restrict__ b1, const float* __restrict__ b2, const float* __restrict__ b3,
    const short* __restrict__ wb1, const short* __restrict__ wb2, const short* __restrict__ wb3,
    float* __restrict__ hout)
{
    __shared__ __align__(16) char lds[40960];
    const int t = threadIdx.x;
    const int lane = t & 63;
    const int w = t >> 6;
    const long pos0 = (long)blockIdx.x * 64;

    const int arow = lane & 15;        // fragment row/col within 16
    const int kgrp = lane >> 4;        // k-group 0..3 (8 bf16 each)
    const int kb = kgrp * 16;          // byte offset of k-group

    // ---- load x tile: 64 rows x 64 f32 -> bf16 swizzled ----
    {
        const int row = t >> 2, q = t & 3;
        const float4* src = (const float4*)(xin + (pos0 + row)*CC + q*16);
        short sv[16];
        #pragma unroll
        for (int i = 0; i < 4; ++i) {
            float4 v = src[i];
            sv[i*4+0] = f2bf(v.x); sv[i*4+1] = f2bf(v.y);
            sv[i*4+2] = f2bf(v.z); sv[i*4+3] = f2bf(v.w);
        }
        const int swz = (row & 7) << 4;
        *(shortx8*)(&lds[row*128 + ((q*32 +  0) ^ swz)]) = *(shortx8*)(&sv[0]);
        *(shortx8*)(&lds[row*128 + ((q*32 + 16) ^ swz)]) = *(shortx8*)(&sv[8]);
    }
    __syncthreads();

    // ---- stage 1: (64x64)x(64x128) -> h1 ----
    {
        const int n0 = w * 32;
        f32x4 acc[4][2];
        #pragma unroll
        for (int m = 0; m < 4; ++m)
            #pragma unroll
            for (int n = 0; n < 2; ++n) acc[m][n] = (f32x4){0.f,0.f,0.f,0.f};
        #pragma unroll
        for (int kk = 0; kk < 2; ++kk) {
            shortx8 a[4];
            #pragma unroll
            for (int m = 0; m < 4; ++m) {
                const int row = m*16 + arow;
                a[m] = *(const shortx8*)(&lds[row*128 + ((kk*64 + kb) ^ ((row & 7) << 4))]);
            }
            #pragma unroll
            for (int n = 0; n < 2; ++n) {
                const shortx8 b = *(const shortx8*)(wb1 + (n0 + n*16 + arow)*64 + kk*32 + kgrp*8);
                #pragma unroll
                for (int m = 0; m < 4; ++m)
                    acc[m][n] = __builtin_amdgcn_mfma_f32_16x16x32_bf16(a[m], b, acc[m][n], 0, 0, 0);
            }
        }
        #pragma unroll
        for (int n = 0; n < 2; ++n) {
            const int col = n0 + n*16 + arow;
            const float bv = b1[col];
            #pragma unroll
            for (int m = 0; m < 4; ++m)
                #pragma unroll
                for (int r = 0; r < 4; ++r) {
                    const int row = m*16 + kgrp*4 + r;
                    *(short*)(&lds[8192 + row*256 + ((col*2) ^ ((row & 7) << 4))]) =
                        f2bf(leaky(acc[m][n][r] + bv));
                }
        }
    }
    __syncthreads();

    // ---- stage 2: (64x128)x(128x128) -> h2 ----
    {
        const int n0 = w * 32;
        f32x4 acc[4][2];
        #pragma unroll
        for (int m = 0; m < 4; ++m)
            #pragma unroll
            for (int n = 0; n < 2; ++n) acc[m][n] = (f32x4){0.f,0.f,0.f,0.f};
        #pragma unroll
        for (int kk = 0; kk < 4; ++kk) {
            shortx8 a[4];
            #pragma unroll
            for (int m = 0; m < 4; ++m) {
                const int row = m*16 + arow;
                a[m] = *(const shortx8*)(&lds[8192 + row*256 + ((kk*64 + kb) ^ ((row & 7) << 4))]);
            }
            #pragma unroll
            for (int n = 0; n < 2; ++n) {
                const shortx8 b = *(const shortx8*)(wb2 + (n0 + n*16 + arow)*128 + kk*32 + kgrp*8);
                #pragma unroll
                for (int m = 0; m < 4; ++m)
                    acc[m][n] = __builtin_amdgcn_mfma_f32_16x16x32_bf16(a[m], b, acc[m][n], 0, 0, 0);
            }
        }
        #pragma unroll
        for (int n = 0; n < 2; ++n) {
            const int col = n0 + n*16 + arow;
            const float bv = b2[col];
            #pragma unroll
            for (int m = 0; m < 4; ++m)
                #pragma unroll
                for (int r = 0; r < 4; ++r) {
                    const int row = m*16 + kgrp*4 + r;
                    *(short*)(&lds[24576 + row*256 + ((col*2) ^ ((row & 7) << 4))]) =
                        f2bf(leaky(acc[m][n][r] + bv));
                }
        }
    }
    __syncthreads();

    // ---- stage 3: (64x128)x(128x64) -> fp32 out tile at LDS base 0 ----
    {
        const int n0 = w * 16;
        f32x4 acc[4];
        #pragma unroll
        for (int m = 0; m < 4; ++m) acc[m] = (f32x4){0.f,0.f,0.f,0.f};
        #pragma unroll
        for (int kk = 0; kk < 4; ++kk) {
            shortx8 a[4];
            #pragma unroll
            for (int m = 0; m < 4; ++m) {
                const int row = m*16 + arow;
                a[m] = *(const shortx8*)(&lds[24576 + row*256 + ((kk*64 + kb) ^ ((row & 7) << 4))]);
            }
            const shortx8 b = *(const shortx8*)(wb3 + (n0 + arow)*128 + kk*32 + kgrp*8);
            #pragma unroll
            for (int m = 0; m < 4; ++m)
                acc[m] = __builtin_amdgcn_mfma_f32_16x16x32_bf16(a[m], b, acc[m], 0, 0, 0);
        }
        const int col = n0 + arow;
        const float bv = b3[col];
        #pragma unroll
        for (int m = 0; m < 4; ++m)
            #pragma unroll
            for (int r = 0; r < 4; ++r) {
                const int row = m*16 + kgrp*4 + r;
                *(float*)(&lds[row*256 + ((col*4) ^ ((row & 7) << 4))]) =
                    leaky(acc[m][r] + bv);
            }
    }
    __syncthreads();

    // ---- coalesced masked store ----
    {
        const int row = t >> 2, q = t & 3;
        const float mv = mask[pos0 + row];
        const int swz = (row & 7) << 4;
        float4* dst = (float4*)(hout + (pos0 + row)*CC + q*16);
        #pragma unroll
        for (int i = 0; i < 4; ++i) {
            float4 v = *(float4*)(&lds[row*256 + ((q*64 + i*16) ^ swz)]);
            v.x *= mv; v.y *= mv; v.z *= mv; v.w *= mv;
            dst[i] = v;
        }
    }
}

// ---------------- reductions: rowsum, colsum, diag ----------------
__global__ __launch_bounds__(256) void reduce_kernel(const float* __restrict__ h,
                                                     float* __restrict__ rowsum,
                                                     float* __restrict__ colsum,
                                                     float* __restrict__ diag) {
    const int br = blockIdx.x;            // n*128 + r
    const int n = br >> 7, r = br & 127;
    const int t = threadIdx.x, c = t & 63, g = t >> 6;
    __shared__ float red[4][64];
    const float* base_row = h + ((long)(n*NN + r) * NN) * CC;
    float acc = 0.f;
    for (int j = g; j < NN; j += 4) acc += base_row[j*CC + c];
    red[g][c] = acc;
    __syncthreads();
    if (t < 64) rowsum[(long)br*CC + c] = red[0][c] + red[1][c] + red[2][c] + red[3][c];
    __syncthreads();
    const float* base_col = h + ((long)n*NN*NN + r) * CC;
    float acc2 = 0.f;
    for (int i = g; i < NN; i += 4) acc2 += base_col[(long)i*NN*CC + c];
    red[g][c] = acc2;
    __syncthreads();
    if (t < 64) {
        colsum[(long)br*CC + c] = red[0][c] + red[1][c] + red[2][c] + red[3][c];
        diag[(long)br*CC + c] = base_row[r*CC + c];
    }
}

// ---------------- trace/total ----------------
__global__ __launch_bounds__(256) void trace_total_kernel(const float* __restrict__ rowsum,
                                                          const float* __restrict__ diag,
                                                          float* __restrict__ trace,
                                                          float* __restrict__ total) {
    const int n = blockIdx.x;
    const int t = threadIdx.x, c = t & 63, g = t >> 6;
    __shared__ float ra[4][64], rb[4][64];
    float a = 0.f, b = 0.f;
    for (int i = g; i < NN; i += 4) {
        a += rowsum[((long)n*NN + i)*CC + c];
        b += diag[((long)n*NN + i)*CC + c];
    }
    ra[g][c] = a; rb[g][c] = b;
    __syncthreads();
    if (t < 64) {
        total[(long)n*CC + c] = ra[0][c] + ra[1][c] + ra[2][c] + ra[3][c];
        trace[(long)n*CC + c] = rb[0][c] + rb[1][c] + rb[2][c] + rb[3][c];
    }
}

// ---------------- U/V/D precompute ----------------
__global__ __launch_bounds__(256) void uvd_kernel(const float* __restrict__ rowsum,
                                                  const float* __restrict__ colsum,
                                                  const float* __restrict__ diag,
                                                  const float* __restrict__ trace,
                                                  const float* __restrict__ total,
                                                  const float* __restrict__ coefs, int layer,
                                                  float* __restrict__ U, float* __restrict__ V,
                                                  float* __restrict__ D) {
    const int bi = blockIdx.x;            // n*128 + i
    const int n = bi >> 7, i = bi & 127;
    const int t = threadIdx.x;
    if (t >= 192) return;
    const int which = t >> 6, s = t & 63;
    const float* cf = coefs + (long)layer*CC*CC*15;
    const long rbase = ((long)n*NN + i)*CC;
    float acc = 0.f;
    for (int d = 0; d < CC; ++d) {
        const float rs = rowsum[rbase + d];
        const float cs = colsum[rbase + d];
        const float dg = diag[rbase + d];
        const float tr = trace[(long)n*CC + d];
        const float tt = total[(long)n*CC + d];
        const float* cds = cf + ((long)d*CC + s)*15;
        if (which == 0)       acc += cds[5]*cs + cds[6]*rs + cds[11]*dg + cds[13]*tr + cds[14]*tt;
        else if (which == 1)  acc += cds[7]*cs + cds[8]*rs + cds[12]*dg;
        else                  acc += cds[0]*dg + cds[1]*tr + cds[2]*rs + cds[3]*cs + cds[4]*tt;
    }
    float* dst = (which == 0) ? U : (which == 1) ? V : D;
    dst[rbase + s] = acc;
}

// ---------------- Eq2to2 finalize: MFMA with split-bf16 (hi/lo) operands ----------------
// out[p,s] = sum_d A[p,d] c9[d,s] + T[p,d] c10[d,s]  + U(i) + V(j) + bias + diag(D + dbias)
// A row p = h[n, i0+(p>>3), j0+(p&7)]; T row p = h[n, j0+(p&7), i0+(p>>3)].
// LDS: Ahi@0, Alo@8192, Thi@16384, Tlo@24576 (each 64x64 bf16, 128B rows, XOR-swizzled).
// Epilogue fp32 tile aliases [0,16384).
__global__ __launch_bounds__(256, 4) void eq_kernel(
    const float* __restrict__ h, const float* __restrict__ mask,
    const short* __restrict__ c9hi, const short* __restrict__ c9lo,
    const short* __restrict__ c10hi, const short* __restrict__ c10lo,
    const float* __restrict__ U, const float* __restrict__ V, const float* __restrict__ D,
    const float* __restrict__ bias, const float* __restrict__ dbias,
    float* __restrict__ out)
{
    __shared__ __align__(16) char lds[32768];
    const int t = threadIdx.x;
    const int lane = t & 63;
    const int w = t >> 6;
    const int arow = lane & 15;
    const int kgrp = lane >> 4;
    const int kb = kgrp * 16;
    const int jt = blockIdx.x, it = blockIdx.y, n = blockIdx.z;
    const int i0 = it*8, j0 = jt*8;

    // ---- stage A and T tiles as hi/lo bf16, swizzled ----
    {
        const int row = t >> 2, q = t & 3;
        const int a = row >> 3, b = row & 7;
        const float4* srcA = (const float4*)(h + (((long)n*NN + i0 + a)*NN + j0 + b)*CC + q*16);
        const float4* srcT = (const float4*)(h + (((long)n*NN + j0 + b)*NN + i0 + a)*CC + q*16);
        const int swz = (row & 7) << 4;
        short hi[16], lo[16];
        #pragma unroll
        for (int i = 0; i < 4; ++i) {
            float4 v = srcA[i];
            float fv[4] = {v.x, v.y, v.z, v.w};
            #pragma unroll
            for (int e = 0; e < 4; ++e) {
                short hh = f2bf(fv[e]);
                hi[i*4+e] = hh;
                lo[i*4+e] = f2bf(fv[e] - bf2f(hh));
            }
        }
        *(shortx8*)(&lds[row*128 + ((q*32 +  0) ^ swz)]) = *(shortx8*)(&hi[0]);
        *(shortx8*)(&lds[row*128 + ((q*32 + 16) ^ swz)]) = *(shortx8*)(&hi[8]);
        *(shortx8*)(&lds[8192 + row*128 + ((q*32 +  0) ^ swz)]) = *(shortx8*)(&lo[0]);
        *(shortx8*)(&lds[8192 + row*128 + ((q*32 + 16) ^ swz)]) = *(shortx8*)(&lo[8]);
        #pragma unroll
        for (int i = 0; i < 4; ++i) {
            float4 v = srcT[i];
            float fv[4] = {v.x, v.y, v.z, v.w};
            #pragma unroll
            for (int e = 0; e < 4; ++e) {
                short hh = f2bf(fv[e]);
                hi[i*4+e] = hh;
                lo[i*4+e] = f2bf(fv[e] - bf2f(hh));
            }
        }
        *(shortx8*)(&lds[16384 + row*128 + ((q*32 +  0) ^ swz)]) = *(shortx8*)(&hi[0]);
        *(shortx8*)(&lds[16384 + row*128 + ((q*32 + 16) ^ swz)]) = *(shortx8*)(&hi[8]);
        *(shortx8*)(&lds[24576 + row*128 + ((q*32 +  0) ^ swz)]) = *(shortx8*)(&lo[0]);
        *(shortx8*)(&lds[24576 + row*128 + ((q*32 + 16) ^ swz)]) = *(shortx8*)(&lo[8]);
    }
    __syncthreads();

    // ---- MFMA: acc = Ahi*(c9hi+c9lo) + Alo*c9hi + Thi*(c10hi+c10lo) + Tlo*c10hi ----
    const int s0 = w * 16;
    f32x4 acc[4];
    #pragma unroll
    for (int m = 0; m < 4; ++m) acc[m] = (f32x4){0.f,0.f,0.f,0.f};
    #pragma unroll
    for (int kk = 0; kk < 2; ++kk) {
        const long boff = (long)(s0 + arow)*64 + kk*32 + kgrp*8;
        const shortx8 b9h  = *(const shortx8*)(c9hi  + boff);
        const shortx8 b9l  = *(const shortx8*)(c9lo  + boff);
        const shortx8 b10h = *(const shortx8*)(c10hi + boff);
        const shortx8 b10l = *(const shortx8*)(c10lo + boff);
        #pragma unroll
        for (int m = 0; m < 4; ++m) {
            const int row = m*16 + arow;
            const int off = (kk*64 + kb) ^ ((row & 7) << 4);
            const shortx8 ah = *(const shortx8*)(&lds[row*128 + off]);
            const shortx8 al = *(const shortx8*)(&lds[8192 + row*128 + off]);
            const shortx8 th = *(const shortx8*)(&lds[16384 + row*128 + off]);
            const shortx8 tl = *(const shortx8*)(&lds[24576 + row*128 + off]);
            acc[m] = __builtin_amdgcn_mfma_f32_16x16x32_bf16(ah, b9h,  acc[m], 0, 0, 0);
            acc[m] = __builtin_amdgcn_mfma_f32_16x16x32_bf16(ah, b9l,  acc[m], 0, 0, 0);
            acc[m] = __builtin_amdgcn_mfma_f32_16x16x32_bf16(al, b9h,  acc[m], 0, 0, 0);
            acc[m] = __builtin_amdgcn_mfma_f32_16x16x32_bf16(th, b10h, acc[m], 0, 0, 0);
            acc[m] = __builtin_amdgcn_mfma_f32_16x16x32_bf16(th, b10l, acc[m], 0, 0, 0);
            acc[m] = __builtin_amdgcn_mfma_f32_16x16x32_bf16(tl, b10h, acc[m], 0, 0, 0);
        }
    }
    __syncthreads();   // all LDS tile reads complete before epilogue aliases [0,16384)

    // ---- epilogue in fragment layout -> fp32 LDS tile ----
    {
        const int col = s0 + arow;
        const float bv = bias[col];
        const float dbv = dbias[col];
        #pragma unroll
        for (int m = 0; m < 4; ++m)
            #pragma unroll
            for (int r = 0; r < 4; ++r) {
                const int p = m*16 + kgrp*4 + r;
                const int i = i0 + (p >> 3), j = j0 + (p & 7);
                float v = acc[m][r] + U[((long)n*NN + i)*CC + col]
                                    + V[((long)n*NN + j)*CC + col] + bv;
                if (i == j) v += D[((long)n*NN + i)*CC + col] + dbv;
                *(float*)(&lds[p*256 + ((col*4) ^ ((p & 7) << 4))]) = leaky(v);
            }
    }
    __syncthreads();

    // ---- coalesced masked store ----
    {
        const int row = t >> 2, q = t & 3;
        const long pix = ((long)n*NN + i0 + (row >> 3))*NN + j0 + (row & 7);
        const float mv = mask[pix];
        const int swz = (row & 7) << 4;
        float4* dst = (float4*)(out + pix*CC + q*16);
        #pragma unroll
        for (int i = 0; i < 4; ++i) {
            float4 v = *(float4*)(&lds[row*256 + ((q*64 + i*16) ^ swz)]);
            v.x *= mv; v.y *= mv; v.z *= mv; v.w *= mv;
            dst[i] = v;
        }
    }
}

extern "C" void kernel_launch(void* const* d_in, const int* in_sizes, int n_in,
                              void* d_out, int out_size, void* d_ws, size_t ws_size,
                              hipStream_t stream) {
    const float* x     = (const float*)d_in[0];
    const float* mask  = (const float*)d_in[1];
    const float* w1    = (const float*)d_in[2];
    const float* b1    = (const float*)d_in[3];
    const float* w2    = (const float*)d_in[4];
    const float* b2    = (const float*)d_in[5];
    const float* w3    = (const float*)d_in[6];
    const float* b3    = (const float*)d_in[7];
    const float* coefs = (const float*)d_in[8];
    const float* bias  = (const float*)d_in[9];
    const float* dbias = (const float*)d_in[10];
    float* out = (float*)d_out;
    float* ws  = (float*)d_ws;

    float* h      = ws + OFF_H;
    float* rowsum = ws + OFF_RS;
    float* colsum = ws + OFF_CS;
    float* diag   = ws + OFF_DG;
    float* trace  = ws + OFF_TR;
    float* total  = ws + OFF_TT;
    float* U      = ws + OFF_U;
    float* V      = ws + OFF_V;
    float* D      = ws + OFF_D;
    short* sb     = (short*)(ws + OFF_WB);

    prep_kernel<<<480, 256, 0, stream>>>(w1, w2, w3, coefs, ws);

    const float* cur = x;
    for (int l = 0; l < LL; ++l) {
        mlp_kernel<<<NPOS/64, 256, 0, stream>>>(
            cur, mask, b1 + l*HH, b2 + l*HH, b3 + l*CC,
            sb + (long)l*HH*CC, sb + 24576 + (long)l*HH*HH, sb + 73728 + (long)l*CC*HH,
            h);
        reduce_kernel<<<BB*NN, 256, 0, stream>>>(h, rowsum, colsum, diag);
        trace_total_kernel<<<BB, 256, 0, stream>>>(rowsum, diag, trace, total);
        uvd_kernel<<<BB*NN, 256, 0, stream>>>(rowsum, colsum, diag, trace, total,
                                              coefs, l, U, V, D);
        eq_kernel<<<dim3(NN/8, NN/8, BB), 256, 0, stream>>>(
            h, mask,
            sb + 98304 + (long)l*CC*CC, sb + 110592 + (long)l*CC*CC,
            sb + 122880 + (long)l*CC*CC, sb + 135168 + (long)l*CC*CC,
            U, V, D, bias + l*CC, dbias + l*CC, out);
        cur = out;
    }
}